// Round 9
// baseline (75.751 us; speedup 1.0000x reference)
//
#include <hip/hip_runtime.h>

// BinaryLinearLayer: C = (sign(X) @ sign(W)) * (relu(alpha)*outer(relu(betta),relu(gamma))).flatten()
// M=8192, K=4096, N=2048.
// fp4 e2m1 (+/-1, 0 exact; unit E8M0 scales) -> mfma_scale_f32_32x32x64_f8f6f4.
// Layout: kslot-major 128-row panels: [panel][kslot 0..127][row 0..127] x 16B
// (kslot = 32 k = 16 B). GEMM: 128x128 tile, BK=128, 4 waves, LDS 32 KB dbuf
// -> 4 blocks/CU (16 waves/CU): rely on wave-level overlap, not manual pipelining.

#define M_DIM 8192
#define K_DIM 4096
#define N_DIM 2048
#define NTK   (K_DIM / 128)          // 32 K-tiles of 128 k
#define PANEL (128 * 128 * 16)       // 256 KB per 128-row/col panel
#define KTILE 8192                   // 4 kslots x 128 rows x 16B

typedef int i32x4 __attribute__((ext_vector_type(4)));
typedef int i32x8 __attribute__((ext_vector_type(8)));
typedef float f32x16 __attribute__((ext_vector_type(16)));

__device__ __forceinline__ unsigned int nib4(float x) {
  // sign(x) as fp4 e2m1 nibble: +1 -> 0x2, -1 -> 0xA, 0 -> 0x0
  unsigned int s = (__float_as_uint(x) >> 28) & 0x8u;
  return x == 0.0f ? 0u : (0x2u | s);
}

__device__ __forceinline__ unsigned int pack8(const float* f) {
  unsigned int p = 0;
#pragma unroll
  for (int j = 0; j < 8; ++j) p |= nib4(f[j]) << (4 * j);
  return p;
}

__device__ __forceinline__ void gload_lds16(const void* g, void* lds) {
  __builtin_amdgcn_global_load_lds(
      (const __attribute__((address_space(1))) unsigned int*)g,
      (__attribute__((address_space(3))) unsigned int*)lds, 16, 0, 0);
}

// ---- binX: X f32 [M][K] -> Xq kslot-major; coalesced via LDS stripe ----
// 4096 blocks: rg = bid>>4 (32 rows), kc = bid&15 (256-k chunk = 8 kslots).
__global__ __launch_bounds__(256) void binX_kernel(
    const float* __restrict__ X, unsigned char* __restrict__ Xq) {
  __shared__ float tile[32][260];   // 1040B row stride: 16B-aligned
  const int t = threadIdx.x;
  const int rg = blockIdx.x >> 4;
  const int kc = blockIdx.x & 15;
  const int lrow = t >> 6;          // 0..3
  const int col4 = (t & 63) * 4;
#pragma unroll
  for (int i = 0; i < 8; ++i)
    *(float4*)&tile[i * 4 + lrow][col4] =
        *(const float4*)&X[(size_t)(rg * 32 + i * 4 + lrow) * K_DIM + kc * 256 + col4];
  __syncthreads();
  const int s = t >> 5;   // 0..7 kslot within chunk
  const int r = t & 31;   // 0..31 row in group
  float f[32];
#pragma unroll
  for (int q = 0; q < 8; ++q)   // float4 reads: 4-way conflict max
    *(float4*)&f[q * 4] = *(const float4*)&tile[r][s * 32 + q * 4];
  uint4 gq;
  gq.x = pack8(f + 0);  gq.y = pack8(f + 8);
  gq.z = pack8(f + 16); gq.w = pack8(f + 24);
  const int row = rg * 32 + r;
  const int kslot = kc * 8 + s;
  unsigned char* dst = Xq + (size_t)(row >> 7) * PANEL +
                       ((size_t)kslot * 128 + (row & 127)) * 16;
  *(uint4*)dst = gq;
}

// ---- binW: W f32 [K][N] -> Wq transpose kslot-major (128-col panels) ----
// 1024 blocks: q = bid>>7 (256-n stripe), kt = (bid>>3)&15, s = bid&7.
__global__ __launch_bounds__(256) void binW_kernel(
    const float* __restrict__ W, unsigned char* __restrict__ Wq) {
  __shared__ float tile[32][260];
  const int t = threadIdx.x;
  const int q = blockIdx.x >> 7;
  const int kt = (blockIdx.x >> 3) & 15;
  const int s = blockIdx.x & 7;
#pragma unroll
  for (int i = 0; i < 8; ++i) {
    int row = i * 4 + (t >> 6);
    int col4 = (t & 63) * 4;
    *(float4*)&tile[row][col4] =
        *(const float4*)&W[(size_t)(kt * 256 + s * 32 + row) * N_DIM + q * 256 + col4];
  }
  __syncthreads();
  float f[32];
#pragma unroll
  for (int k = 0; k < 32; ++k) f[k] = tile[k][t];   // 2-way: free
  uint4 gq;
  gq.x = pack8(f + 0);  gq.y = pack8(f + 8);
  gq.z = pack8(f + 16); gq.w = pack8(f + 24);
  const int n = q * 256 + t;
  const int kslot = kt * 8 + s;
  unsigned char* dst = Wq + (size_t)(n >> 7) * PANEL +
                       ((size_t)kslot * 128 + (n & 127)) * 16;
  *(uint4*)dst = gq;
}

// stage A(8KB)+B(8KB) K-tile into LDS: linear copies, 4 gloads/thread
__device__ __forceinline__ void stage_tiles(const unsigned char* __restrict__ Asrc,
                                            const unsigned char* __restrict__ Bsrc,
                                            unsigned char* lds, int t) {
#pragma unroll
  for (int p = 0; p < 2; ++p) {
    int c = p * 256 + t;
    gload_lds16(Asrc + c * 16, lds + c * 16);
    gload_lds16(Bsrc + c * 16, lds + 8192 + c * 16);
  }
}

// ---------------- GEMM: C[M][N] = Xq * Wq^T (fp4 MX, unit scales) ----------
// 128x128 tile, BK=128, 4 waves (2x2), wave tile 64x64 = 2x2 frags 32x32x64.
// LDS 32 KB dbuf -> 4 blocks/CU. Simple loop: stage(next) -> compute(cur) ->
// drain+barrier. No manual waits: compiler + wave-level overlap schedule it.
__global__ __launch_bounds__(256, 4) void gemm_fp4_kernel(
    const unsigned char* __restrict__ Aq,
    const unsigned char* __restrict__ Bq,
    const float* __restrict__ alpha,
    const float* __restrict__ betta,
    const float* __restrict__ gamma,
    float* __restrict__ C) {
  __shared__ __align__(16) unsigned char smem[32768];  // 2 x (A 8KB + B 8KB)

  const int t = threadIdx.x;
  const int lane = t & 63;
  const int l31 = lane & 31;
  const int lhi = lane >> 5;
  const int w = t >> 6;          // 0..3
  const int wr = w >> 1;         // 0..1
  const int wc = w & 1;          // 0..1

  // bijective XCD decode: xcd = bid&7 owns bm in {8x..8x+7} x all 16 bn.
  // Per K-step unique fetch per XCD: (8+16) x 8KB = 192 KB -> L2-resident.
  const int bid = blockIdx.x;
  const int j = bid >> 3;          // 0..127
  const int bn = j & 15;           // 0..15
  const int bm = (bid & 7) * 8 + (j >> 4);  // 0..63
  const int row0 = bm * 128;
  const int col0 = bn * 128;

  const unsigned char* Abase = Aq + (size_t)bm * PANEL;
  const unsigned char* Bbase = Bq + (size_t)bn * PANEL;

  f32x16 acc[2][2];
#pragma unroll
  for (int fm = 0; fm < 2; ++fm)
#pragma unroll
    for (int fn = 0; fn < 2; ++fn)
#pragma unroll
      for (int r = 0; r < 16; ++r) acc[fm][fn][r] = 0.f;

  // operand tuples: top half zeroed once, low half overwritten per phase
  i32x8 a8[2], b8[2];
#pragma unroll
  for (int i = 0; i < 2; ++i)
#pragma unroll
    for (int e = 0; e < 8; ++e) { a8[i][e] = 0; b8[i][e] = 0; }

  // prologue: stage K-tile 0 into buf0
  stage_tiles(Abase, Bbase, &smem[0], t);
  asm volatile("s_waitcnt vmcnt(0)" ::: "memory");
  __builtin_amdgcn_s_barrier();

  for (int kt = 0; kt < NTK; ++kt) {
    const int cur = kt & 1;
    const unsigned char* pA = &smem[cur * 16384];
    const unsigned char* pB = pA + 8192;

    // issue next-tile stage first: loads fly under this tile's compute
    if (kt + 1 < NTK)
      stage_tiles(Abase + (kt + 1) * KTILE, Bbase + (kt + 1) * KTILE,
                  &smem[(cur ^ 1) * 16384], t);

#pragma unroll
    for (int kk = 0; kk < 2; ++kk) {
      const int g = kk * 2 + lhi;   // kslot 0..3
#pragma unroll
      for (int fm = 0; fm < 2; ++fm)
        *(i32x4*)&a8[fm] = *(const i32x4*)&pA[(g * 128 + wr * 64 + fm * 32 + l31) * 16];
#pragma unroll
      for (int fn = 0; fn < 2; ++fn)
        *(i32x4*)&b8[fn] = *(const i32x4*)&pB[(g * 128 + wc * 64 + fn * 32 + l31) * 16];
#pragma unroll
      for (int fm = 0; fm < 2; ++fm)
#pragma unroll
        for (int fn = 0; fn < 2; ++fn)
          acc[fm][fn] = __builtin_amdgcn_mfma_scale_f32_32x32x64_f8f6f4(
              a8[fm], b8[fn], acc[fm][fn], 4, 4,   // cbsz=fp4, blgp=fp4
              0, 0x7F7F7F7F, 0, 0x7F7F7F7F);       // unit E8M0 scales
    }

    // tile boundary: next-tile loads landed; swap buffers
    asm volatile("s_waitcnt vmcnt(0)" ::: "memory");
    __builtin_amdgcn_s_barrier();
  }

  // epilogue: scale[col] = relu(alpha)*relu(betta[col/64])*relu(gamma[col%64])
  const float ra = fmaxf(alpha[0], 0.0f);
#pragma unroll
  for (int fn = 0; fn < 2; ++fn) {
    const int col = col0 + wc * 64 + fn * 32 + l31;
    const float sc = ra * fmaxf(betta[col >> 6], 0.0f) * fmaxf(gamma[col & 63], 0.0f);
#pragma unroll
    for (int fm = 0; fm < 2; ++fm) {
      const int rbase = row0 + wr * 64 + fm * 32 + 4 * lhi;
#pragma unroll
      for (int r = 0; r < 16; ++r) {
        const int row = rbase + (r & 3) + 8 * (r >> 2);
        C[(size_t)row * N_DIM + col] = acc[fm][fn][r] * sc;
      }
    }
  }
}

extern "C" void kernel_launch(void* const* d_in, const int* in_sizes, int n_in,
                              void* d_out, int out_size, void* d_ws, size_t ws_size,
                              hipStream_t stream) {
  const float* X = (const float*)d_in[0];      // [8192][4096]
  const float* W = (const float*)d_in[1];      // [4096][2048]
  const float* alpha = (const float*)d_in[2];  // [1]
  const float* betta = (const float*)d_in[3];  // [32]
  const float* gamma = (const float*)d_in[4];  // [64]
  float* out = (float*)d_out;                  // [8192][2048]

  unsigned char* Xq = (unsigned char*)d_ws;                  // 16 MiB
  unsigned char* Wq = Xq + (size_t)(M_DIM / 128) * PANEL;    // 4 MiB

  binW_kernel<<<1024, 256, 0, stream>>>(W, Wq);
  binX_kernel<<<4096, 256, 0, stream>>>(X, Xq);
  gemm_fp4_kernel<<<(M_DIM / 128) * (N_DIM / 128), 256, 0, stream>>>(
      Xq, Wq, alpha, betta, gamma, out);
}

// Round 10
// 72.818 us; speedup vs baseline: 1.0403x; 1.0403x over previous
//
#include <hip/hip_runtime.h>

// BinaryLinearLayer: C = (sign(X) @ sign(W)) * (relu(alpha)*outer(relu(betta),relu(gamma))).flatten()
// M=8192, K=4096, N=2048.
// fp4 e2m1 (+/-1, 0 exact; unit E8M0 scales) -> mfma_scale_f32_32x32x64_f8f6f4.
// Layout: kslot-major 128-row panels: [panel][kslot 0..127][row 0..127] x 16B.
// GEMM: 256x128 tile, BK=128, 4 waves (wave 128x64 = 4x2 frags), LDS 3x24KB,
// COUNTED vmcnt(6) main loop (T4: loads in flight across barriers, never drain),
// one raw s_barrier per K-tile, stage issued 2 tiles ahead.

#define M_DIM 8192
#define K_DIM 4096
#define N_DIM 2048
#define NTK   (K_DIM / 128)          // 32 K-tiles of 128 k
#define PANEL (128 * 128 * 16)       // 256 KB per 128-row/col panel
#define KSTEP 8192                   // bytes per panel per K-tile (4 kslots x 128 x 16B)
#define BUFB  24576                  // LDS buffer: A0 8KB + A1 8KB + B 8KB

typedef int i32x4 __attribute__((ext_vector_type(4)));
typedef int i32x8 __attribute__((ext_vector_type(8)));
typedef float f32x16 __attribute__((ext_vector_type(16)));

__device__ __forceinline__ unsigned int nib4(float x) {
  // sign(x) as fp4 e2m1 nibble: +1 -> 0x2, -1 -> 0xA, 0 -> 0x0
  unsigned int s = (__float_as_uint(x) >> 28) & 0x8u;
  return x == 0.0f ? 0u : (0x2u | s);
}

__device__ __forceinline__ unsigned int pack8(const float* f) {
  unsigned int p = 0;
#pragma unroll
  for (int j = 0; j < 8; ++j) p |= nib4(f[j]) << (4 * j);
  return p;
}

__device__ __forceinline__ void gload_lds16(const void* g, void* lds) {
  __builtin_amdgcn_global_load_lds(
      (const __attribute__((address_space(1))) unsigned int*)g,
      (__attribute__((address_space(3))) unsigned int*)lds, 16, 0, 0);
}

// ---- binX: X f32 [M][K] -> Xq kslot-major; coalesced via LDS stripe ----
__global__ __launch_bounds__(256) void binX_kernel(
    const float* __restrict__ X, unsigned char* __restrict__ Xq) {
  __shared__ float tile[32][260];
  const int t = threadIdx.x;
  const int rg = blockIdx.x >> 4;
  const int kc = blockIdx.x & 15;
  const int lrow = t >> 6;
  const int col4 = (t & 63) * 4;
#pragma unroll
  for (int i = 0; i < 8; ++i)
    *(float4*)&tile[i * 4 + lrow][col4] =
        *(const float4*)&X[(size_t)(rg * 32 + i * 4 + lrow) * K_DIM + kc * 256 + col4];
  __syncthreads();
  const int s = t >> 5;
  const int r = t & 31;
  float f[32];
#pragma unroll
  for (int q = 0; q < 8; ++q)
    *(float4*)&f[q * 4] = *(const float4*)&tile[r][s * 32 + q * 4];
  uint4 gq;
  gq.x = pack8(f + 0);  gq.y = pack8(f + 8);
  gq.z = pack8(f + 16); gq.w = pack8(f + 24);
  const int row = rg * 32 + r;
  const int kslot = kc * 8 + s;
  unsigned char* dst = Xq + (size_t)(row >> 7) * PANEL +
                       ((size_t)kslot * 128 + (row & 127)) * 16;
  *(uint4*)dst = gq;
}

// ---- binW: W f32 [K][N] -> Wq transpose kslot-major (128-col panels) ----
__global__ __launch_bounds__(256) void binW_kernel(
    const float* __restrict__ W, unsigned char* __restrict__ Wq) {
  __shared__ float tile[32][260];
  const int t = threadIdx.x;
  const int q = blockIdx.x >> 7;
  const int kt = (blockIdx.x >> 3) & 15;
  const int s = blockIdx.x & 7;
#pragma unroll
  for (int i = 0; i < 8; ++i) {
    int row = i * 4 + (t >> 6);
    int col4 = (t & 63) * 4;
    *(float4*)&tile[row][col4] =
        *(const float4*)&W[(size_t)(kt * 256 + s * 32 + row) * N_DIM + q * 256 + col4];
  }
  __syncthreads();
  float f[32];
#pragma unroll
  for (int k = 0; k < 32; ++k) f[k] = tile[k][t];
  uint4 gq;
  gq.x = pack8(f + 0);  gq.y = pack8(f + 8);
  gq.z = pack8(f + 16); gq.w = pack8(f + 24);
  const int n = q * 256 + t;
  const int kslot = kt * 8 + s;
  unsigned char* dst = Wq + (size_t)(n >> 7) * PANEL +
                       ((size_t)kslot * 128 + (n & 127)) * 16;
  *(uint4*)dst = gq;
}

// ---------------- GEMM: C[M][N] = Xq * Wq^T (fp4 MX, unit scales) ----------
__global__ __launch_bounds__(256, 2) void gemm_fp4_kernel(
    const unsigned char* __restrict__ Aq,
    const unsigned char* __restrict__ Bq,
    const float* __restrict__ alpha,
    const float* __restrict__ betta,
    const float* __restrict__ gamma,
    float* __restrict__ C) {
  __shared__ __align__(16) unsigned char smem[3 * BUFB];  // 72 KB, 3-deep

  const int t = threadIdx.x;
  const int lane = t & 63;
  const int l31 = lane & 31;
  const int lhi = lane >> 5;
  const int w = t >> 6;          // 0..3
  const int wr = w >> 1;         // 0..1 (128-row half of 256)
  const int wc = w & 1;          // 0..1 (64-col half of 128)

  // XCD decode: xcd = bid&7 owns bm {4x..4x+3} x all 16 bn (bijective).
  const int bid = blockIdx.x;            // 512 blocks
  const int j = bid >> 3;                // 0..63
  const int bm = (bid & 7) * 4 + (j & 3);  // 0..31 (256-row tiles)
  const int bn = j >> 2;                   // 0..15 (128-col tiles)
  const int row0 = bm * 256;
  const int col0 = bn * 128;

  const unsigned char* Asrc0 = Aq + (size_t)(2 * bm) * PANEL;
  const unsigned char* Asrc1 = Asrc0 + PANEL;
  const unsigned char* Bsrc  = Bq + (size_t)bn * PANEL;

  f32x16 acc[4][2];
#pragma unroll
  for (int fm = 0; fm < 4; ++fm)
#pragma unroll
    for (int fn = 0; fn < 2; ++fn)
#pragma unroll
      for (int r = 0; r < 16; ++r) acc[fm][fn][r] = 0.f;

  // persistent operand tuples: top halves zeroed once (fp4 uses low 4 regs)
  i32x8 a8[4], b8[2];
#pragma unroll
  for (int i = 0; i < 4; ++i)
#pragma unroll
    for (int e = 0; e < 8; ++e) a8[i][e] = 0;
#pragma unroll
  for (int i = 0; i < 2; ++i)
#pragma unroll
    for (int e = 0; e < 8; ++e) b8[i][e] = 0;

  // stage one K-tile (A 16KB + B 8KB) into buf: 6 gload_lds16 per thread
  auto stage = [&](int kt, unsigned char* buf) {
    const unsigned char* a0 = Asrc0 + kt * KSTEP;
    const unsigned char* a1 = Asrc1 + kt * KSTEP;
    const unsigned char* b  = Bsrc  + kt * KSTEP;
#pragma unroll
    for (int p = 0; p < 2; ++p) {
      const int c = p * 256 + t;
      gload_lds16(a0 + c * 16, buf + c * 16);
      gload_lds16(a1 + c * 16, buf + 8192 + c * 16);
      gload_lds16(b  + c * 16, buf + 16384 + c * 16);
    }
  };

  auto compute = [&](const unsigned char* buf) {
    const unsigned char* pA = buf + wr * 8192;
    const unsigned char* pB = buf + 16384;
#pragma unroll
    for (int kk = 0; kk < 2; ++kk) {
      const int g = kk * 2 + lhi;  // kslot 0..3
#pragma unroll
      for (int fm = 0; fm < 4; ++fm)
        *(i32x4*)&a8[fm] = *(const i32x4*)&pA[(g * 128 + fm * 32 + l31) * 16];
#pragma unroll
      for (int fn = 0; fn < 2; ++fn)
        *(i32x4*)&b8[fn] = *(const i32x4*)&pB[(g * 128 + wc * 64 + fn * 32 + l31) * 16];
      __builtin_amdgcn_s_setprio(1);
#pragma unroll
      for (int fm = 0; fm < 4; ++fm)
#pragma unroll
        for (int fn = 0; fn < 2; ++fn)
          acc[fm][fn] = __builtin_amdgcn_mfma_scale_f32_32x32x64_f8f6f4(
              a8[fm], b8[fn], acc[fm][fn], 4, 4,   // cbsz=fp4, blgp=fp4
              0, 0x7F7F7F7F, 0, 0x7F7F7F7F);       // unit E8M0 scales
      __builtin_amdgcn_s_setprio(0);
    }
  };

  unsigned char* P0 = smem;
  unsigned char* P1 = smem + BUFB;
  unsigned char* P2 = smem + 2 * BUFB;

  // prologue: 2 tiles in flight
  stage(0, P0);
  stage(1, P1);

  for (int kt = 0; kt < NTK - 1; ++kt) {
    // T4: wait until <=6 loads outstanding (= stage(kt+1) still flying,
    // stage(kt) complete). NEVER vmcnt(0) in the main loop.
    asm volatile("s_waitcnt vmcnt(6)" ::: "memory");
    __builtin_amdgcn_s_barrier();          // publishes stage(kt) to all waves
    __builtin_amdgcn_sched_barrier(0);     // no ds_read hoisted above barrier
    if (kt + 2 < NTK) stage(kt + 2, P2);   // P2 = buf(kt-1): all done reading
    compute(P0);
    unsigned char* tmp = P0; P0 = P1; P1 = P2; P2 = tmp;
  }
  // peeled last tile: full drain
  asm volatile("s_waitcnt vmcnt(0)" ::: "memory");
  __builtin_amdgcn_s_barrier();
  __builtin_amdgcn_sched_barrier(0);
  compute(P0);

  // epilogue: scale[col] = relu(alpha)*relu(betta[col/64])*relu(gamma[col%64])
  const float ra = fmaxf(alpha[0], 0.0f);
#pragma unroll
  for (int fn = 0; fn < 2; ++fn) {
    const int col = col0 + wc * 64 + fn * 32 + l31;
    const float sc = ra * fmaxf(betta[col >> 6], 0.0f) * fmaxf(gamma[col & 63], 0.0f);
#pragma unroll
    for (int fm = 0; fm < 4; ++fm) {
      const int rbase = row0 + wr * 128 + fm * 32 + 4 * lhi;
#pragma unroll
      for (int r = 0; r < 16; ++r) {
        const int row = rbase + (r & 3) + 8 * (r >> 2);
        C[(size_t)row * N_DIM + col] = acc[fm][fn][r] * sc;
      }
    }
  }
}

extern "C" void kernel_launch(void* const* d_in, const int* in_sizes, int n_in,
                              void* d_out, int out_size, void* d_ws, size_t ws_size,
                              hipStream_t stream) {
  const float* X = (const float*)d_in[0];      // [8192][4096]
  const float* W = (const float*)d_in[1];      // [4096][2048]
  const float* alpha = (const float*)d_in[2];  // [1]
  const float* betta = (const float*)d_in[3];  // [32]
  const float* gamma = (const float*)d_in[4];  // [64]
  float* out = (float*)d_out;                  // [8192][2048]

  unsigned char* Xq = (unsigned char*)d_ws;                  // 16 MiB
  unsigned char* Wq = Xq + (size_t)(M_DIM / 128) * PANEL;    // 4 MiB

  binW_kernel<<<1024, 256, 0, stream>>>(W, Wq);
  binX_kernel<<<4096, 256, 0, stream>>>(X, Xq);
  gemm_fp4_kernel<<<(M_DIM / 256) * (N_DIM / 128), 256, 0, stream>>>(
      Xq, Wq, alpha, betta, gamma, out);
}